// Round 14
// baseline (122.099 us; speedup 1.0000x reference)
//
#include <hip/hip_runtime.h>
#include <math.h>

#define N_NODES 12000
#define F_INN 16
#define HIDD 64
#define NCLUST 100
#define NEDGE 384000
#define NBLK_N 47          // ceil(12000/256)
#define NGRP 8             // bucket groups, keyed by blockIdx&7 (~XCD under round-robin)
#define CAP_G 24           // slots per group = 3 cache lines exactly (P(overflow)~1e-9)
#define CAPT (NGRP * CAP_G)            // 192 slots per node
#define NROUND 6                       // 192/32 gather rounds (fixed trip count)
#define EPT 4              // edges per thread in edge passes
#define NBLK_E 375         // (NEDGE/EPT)/256
#define NBLK_F1 (N_NODES / 4)          // 3000 (4 nodes/block, 256 threads)
#define NBLK_F2 (N_NODES / 8)          // 1500 (8 nodes/block, 512 threads)

// ws layout (4-byte element offsets):
#define OFF_COUNT   0        // 8*12000 int (memset each call)
#define OFF_SCAL    96000    // 2 f32      (memset each call)
#define ZERO_ELEMS  96002
#define OFF_SSPART  96004    // 12032 f32
#define OFF_NORM2   108036   // 12000 f32
#define OFF_W2TREL  120036   // 6400 f32  (W2_rel transposed [64][100])
#define OFF_W2TROOT 126436   // 6400 f32
#define OFF_SMC     132836   // 192000 f32
#define OFF_H       324836   // 768000 f32
#define OFF_SRCW    1092836  // 12000*192 int2 (byte off 4371344, 8B aligned)

// ---------------- phase0: smc softmax+norm2 | bucket-fill (group-local) | W2 transpose
__global__ void phase0_kernel(const float* __restrict__ x, const int* __restrict__ ei,
                              const float* __restrict__ ew, float* __restrict__ smc,
                              float* __restrict__ norm2, int* __restrict__ count,
                              int2* __restrict__ srcw, const float* __restrict__ W2_rel,
                              const float* __restrict__ W2_root, float* __restrict__ w2t_rel,
                              float* __restrict__ w2t_root) {
    __shared__ float fl[6400];
    int t = threadIdx.x;
    int b = blockIdx.x;
    if (b < NBLK_N) {
        int i = b * 256 + t;
        if (i >= N_NODES) return;
        const float4* xr = (const float4*)(x + i * 16);
        float4 r0 = xr[0], r1 = xr[1], r2 = xr[2], r3 = xr[3];
        float v[16] = {r0.x, r0.y, r0.z, r0.w, r1.x, r1.y, r1.z, r1.w,
                       r2.x, r2.y, r2.z, r2.w, r3.x, r3.y, r3.z, r3.w};
        float m = v[0];
#pragma unroll
        for (int k = 1; k < 16; ++k) m = fmaxf(m, v[k]);
        float s = 0.f;
#pragma unroll
        for (int k = 0; k < 16; ++k) { v[k] = __expf(v[k] - m); s += v[k]; }
        float inv = 1.f / s;
        float n2 = 0.f;
#pragma unroll
        for (int k = 0; k < 16; ++k) { v[k] *= inv; n2 += v[k] * v[k]; }
        float4* so = (float4*)(smc + i * 16);
        so[0] = make_float4(v[0], v[1], v[2], v[3]);
        so[1] = make_float4(v[4], v[5], v[6], v[7]);
        so[2] = make_float4(v[8], v[9], v[10], v[11]);
        so[3] = make_float4(v[12], v[13], v[14], v[15]);
        norm2[i] = n2;
    } else if (b < NBLK_N + NBLK_E) {
        // group-local bucket fill: group g = blockIdx&7 -> same XCD under round-robin.
        // All atomics/stores of group g touch only g's private count region and its
        // exclusive 3-line bucket segment -> lines merge in one L2, no cross-XCD ping-pong.
        int g = b & (NGRP - 1);
        int* cg = count + g * N_NODES;
        int tid = (b - NBLK_N) * 256 + t;
        int e0 = tid * EPT;
        int4 sv = *(const int4*)(ei + e0);
        int4 dv = *(const int4*)(ei + NEDGE + e0);
        float4 wv = *(const float4*)(ew + e0);
        int s[EPT] = {sv.x, sv.y, sv.z, sv.w};
        int d[EPT] = {dv.x, dv.y, dv.z, dv.w};
        float w[EPT] = {wv.x, wv.y, wv.z, wv.w};
        int pos[EPT];
#pragma unroll
        for (int i = 0; i < EPT; ++i) pos[i] = atomicAdd(&cg[d[i]], 1);
#pragma unroll
        for (int i = 0; i < EPT; ++i)
            if (pos[i] < CAP_G)
                srcw[d[i] * CAPT + g * CAP_G + pos[i]] = make_int2(s[i], __float_as_int(w[i]));
    } else {
        const float* src = (b == NBLK_N + NBLK_E) ? W2_rel : W2_root;
        float* dst = (b == NBLK_N + NBLK_E) ? w2t_rel : w2t_root;
        for (int i = t; i < 6400; i += 256) fl[i] = src[i];
        __syncthreads();
        for (int j = t; j < 6400; j += 256) {
            int kk = j / 100, cl = j - kk * 100;
            dst[j] = fl[cl * 64 + kk];
        }
    }
}

// ---------------- merged: fused layer 1 | ss partials | mincut edge reduction
// fused1 gather: fixed 6 predicated rounds over 192 group-slots (validity from LDS lens).
__global__ void fused1_pass2_kernel(const float* __restrict__ x, const int2* __restrict__ srcw,
                                    const int* __restrict__ count, const float* __restrict__ W1_rel,
                                    const float* __restrict__ W1_root, const float* __restrict__ b1,
                                    float* __restrict__ h, const float* __restrict__ smc,
                                    float* __restrict__ sspart, const int* __restrict__ ei,
                                    const float* __restrict__ ew, const float* __restrict__ norm2,
                                    float* __restrict__ scal) {
    __shared__ float shm[4352];
    int t = threadIdx.x;
    int b = blockIdx.x;
    if (b < NBLK_F1) {
        float* wrelT  = shm;          // 16*64
        float* wrootT = shm + 1024;   // 16*64
        float* b1s    = shm + 2048;   // 64
        float* aggr   = shm + 2112;   // [4][16]
        float* xs     = shm + 2176;   // [4][16]
        int*  lensS   = (int*)(shm + 2240);  // [4][8]
        for (int idx = t; idx < 1024; idx += 256) {
            int f = idx >> 4, k = idx & 15;
            wrelT[(k << 6) + f]  = W1_rel[idx];
            wrootT[(k << 6) + f] = W1_root[idx];
        }
        if (t < 64) b1s[t] = b1[t];
        if (t < 32) {
            int nn2 = t >> 3, g = t & 7;
            lensS[nn2 * 8 + g] = count[g * N_NODES + (b * 4 + nn2)];
        }
        __syncthreads();
        int w = t >> 6, lane = t & 63;
        int j2 = lane >> 2;   // slot lane-group 0..15
        int q  = lane & 3;    // float4 chunk of the 16-float x row
        int n = b * 4 + w;
        const int2* bucket = srcw + n * CAPT;
        const int* lp = lensS + w * 8;
        float4 acc4 = make_float4(0.f, 0.f, 0.f, 0.f);
#pragma unroll
        for (int k = 0; k < NROUND; ++k) {   // fixed trip count -> full unroll + pipelining
            int ia = k * 32 + j2, ib = k * 32 + 16 + j2;
            int ga = ia / CAP_G, oa = ia - ga * CAP_G;
            int gb = ib / CAP_G, ob = ib - gb * CAP_G;
            int2 pa = bucket[ia];
            int2 pb = bucket[ib];
            if (oa >= lp[ga]) pa = make_int2(0, 0);   // w=0 -> fma identity
            if (ob >= lp[gb]) pb = make_int2(0, 0);
            float4 va = *(const float4*)(x + pa.x * 16 + q * 4);
            float4 vb = *(const float4*)(x + pb.x * 16 + q * 4);
            float wa = __int_as_float(pa.y), wb = __int_as_float(pb.y);
            acc4.x = fmaf(va.x, wa, acc4.x); acc4.y = fmaf(va.y, wa, acc4.y);
            acc4.z = fmaf(va.z, wa, acc4.z); acc4.w = fmaf(va.w, wa, acc4.w);
            acc4.x = fmaf(vb.x, wb, acc4.x); acc4.y = fmaf(vb.y, wb, acc4.y);
            acc4.z = fmaf(vb.z, wb, acc4.z); acc4.w = fmaf(vb.w, wb, acc4.w);
        }
        acc4.x += __shfl_xor(acc4.x, 4);  acc4.y += __shfl_xor(acc4.y, 4);
        acc4.z += __shfl_xor(acc4.z, 4);  acc4.w += __shfl_xor(acc4.w, 4);
        acc4.x += __shfl_xor(acc4.x, 8);  acc4.y += __shfl_xor(acc4.y, 8);
        acc4.z += __shfl_xor(acc4.z, 8);  acc4.w += __shfl_xor(acc4.w, 8);
        acc4.x += __shfl_xor(acc4.x, 16); acc4.y += __shfl_xor(acc4.y, 16);
        acc4.z += __shfl_xor(acc4.z, 16); acc4.w += __shfl_xor(acc4.w, 16);
        acc4.x += __shfl_xor(acc4.x, 32); acc4.y += __shfl_xor(acc4.y, 32);
        acc4.z += __shfl_xor(acc4.z, 32); acc4.w += __shfl_xor(acc4.w, 32);
        if (j2 == 0) *(float4*)(aggr + w * 16 + q * 4) = acc4;
        if (lane < 16) xs[w * 16 + lane] = x[n * 16 + lane];
        __syncthreads();
        float o = b1s[lane];
#pragma unroll
        for (int kk = 0; kk < 16; ++kk)
            o = fmaf(aggr[w * 16 + kk], wrelT[(kk << 6) + lane],
                     fmaf(xs[w * 16 + kk], wrootT[(kk << 6) + lane], o));
        h[n * 64 + lane] = fmaxf(o, 0.f);
    } else if (b < NBLK_F1 + NBLK_N) {
        int bb = b - NBLK_F1;
        float* rows = shm;            // 256*17
        int n = bb * 256 + t;
        float* rp = rows + t * 17;
        if (n < N_NODES) {
            const float4* sr = (const float4*)(smc + n * 16);
            float4 a0 = sr[0], a1 = sr[1], a2v = sr[2], a3 = sr[3];
            rp[0] = a0.x;  rp[1] = a0.y;  rp[2] = a0.z;  rp[3] = a0.w;
            rp[4] = a1.x;  rp[5] = a1.y;  rp[6] = a1.z;  rp[7] = a1.w;
            rp[8] = a2v.x; rp[9] = a2v.y; rp[10] = a2v.z; rp[11] = a2v.w;
            rp[12] = a3.x; rp[13] = a3.y; rp[14] = a3.z; rp[15] = a3.w;
        } else {
#pragma unroll
            for (int k = 0; k < 16; ++k) rp[k] = 0.f;
        }
        __syncthreads();
        int a = t & 15, bq = t >> 4;
        float accs = 0.f;
#pragma unroll 4
        for (int r = 0; r < 256; ++r)
            accs = fmaf(rows[r * 17 + a], rows[r * 17 + bq], accs);
        sspart[bb * 256 + t] = accs;
    } else {
        int tid = (b - NBLK_F1 - NBLK_N) * 256 + t;
        int e0 = tid * EPT;
        int4 sv = *(const int4*)(ei + e0);
        int4 dv = *(const int4*)(ei + NEDGE + e0);
        float4 wv = *(const float4*)(ew + e0);
        int s[EPT] = {sv.x, sv.y, sv.z, sv.w};
        int d[EPT] = {dv.x, dv.y, dv.z, dv.w};
        float w[EPT] = {wv.x, wv.y, wv.z, wv.w};
        float np = 0.f, dp = 0.f;
#pragma unroll
        for (int i = 0; i < EPT; ++i) {
            const float4* ps = (const float4*)(smc + s[i] * 16);
            const float4* pd = (const float4*)(smc + d[i] * 16);
            float4 s0 = ps[0], s1 = ps[1], s2 = ps[2], s3 = ps[3];
            float4 d0 = pd[0], d1 = pd[1], d2 = pd[2], d3 = pd[3];
            float dot = s0.x * d0.x + s0.y * d0.y + s0.z * d0.z + s0.w * d0.w +
                        s1.x * d1.x + s1.y * d1.y + s1.z * d1.z + s1.w * d1.w +
                        s2.x * d2.x + s2.y * d2.y + s2.z * d2.z + s2.w * d2.w +
                        s3.x * d3.x + s3.y * d3.y + s3.z * d3.z + s3.w * d3.w;
            np = fmaf(w[i], dot, np);
            dp = fmaf(w[i], norm2[s[i]], dp);
        }
        float* redn = shm;
        float* redd = shm + 256;
        redn[t] = np;
        redd[t] = dp;
        __syncthreads();
        for (int s2 = 128; s2 > 0; s2 >>= 1) {
            if (t < s2) { redn[t] += redn[t + s2]; redd[t] += redd[t + s2]; }
            __syncthreads();
        }
        if (t == 0) {
            atomicAdd(&scal[0], redn[0]);
            atomicAdd(&scal[1], redd[0]);
        }
    }
}

// ---------------- merged: fused layer 2 (8 nodes/block, W2_rel staged in LDS) | finalize
// gather: fixed 6 predicated rounds over 192 group-slots.
__global__ __launch_bounds__(512) void fused2_finalize_kernel(
    const float* __restrict__ h, const int2* __restrict__ srcw, const int* __restrict__ count,
    const float* __restrict__ w2t_rel, const float* __restrict__ w2t_root,
    const float* __restrict__ b2, float* __restrict__ out, const float* __restrict__ sspart,
    const float* __restrict__ scal) {
    __shared__ float wsrel[6400];   // w2t_rel staged (25.6 KB); finalize reuses as red[]
    __shared__ float a2[8][64], hrow[8][64];
    __shared__ float logits[8][104];
    __shared__ float b2s[104];
    __shared__ int lensS[64];       // [8 nodes][8 groups]
    int t = threadIdx.x;
    int b = blockIdx.x;
    if (b < NBLK_F2) {
        for (int i = t; i < 6400; i += 512) wsrel[i] = w2t_rel[i];
        if (t < NCLUST) b2s[t] = b2[t];
        if (t >= 128 && t < 192) {
            int nn2 = (t - 128) >> 3, g = t & 7;
            lensS[nn2 * 8 + g] = count[g * N_NODES + (b * 8 + nn2)];
        }
        __syncthreads();
        int nn = t >> 6;            // wave id = node slot 0..7
        int c = t & 63;
        int eslot = c >> 4;         // slot lane-group 0..3
        int q = c & 15;             // float4 chunk of the 64-float h row
        int n = b * 8 + nn;
        const int2* bucket = srcw + n * CAPT;
        const int* lp = lensS + nn * 8;
        float4 acc4 = make_float4(0.f, 0.f, 0.f, 0.f);
#pragma unroll 2
        for (int k = 0; k < NROUND; ++k) {   // fixed trip count; 32 slots/round
            int kb = k * 32;
            int i0 = kb + eslot,      i1 = kb + 4 + eslot;
            int i2 = kb + 8 + eslot,  i3 = kb + 12 + eslot;
            int i4 = kb + 16 + eslot, i5 = kb + 20 + eslot;
            int i6 = kb + 24 + eslot, i7 = kb + 28 + eslot;
            int2 pa = bucket[i0]; int2 pb = bucket[i1];
            int2 pc = bucket[i2]; int2 pd = bucket[i3];
            int2 pe = bucket[i4]; int2 pf = bucket[i5];
            int2 pg = bucket[i6]; int2 ph = bucket[i7];
            int g0 = i0 / CAP_G, g1 = i1 / CAP_G, g2 = i2 / CAP_G, g3 = i3 / CAP_G;
            int g4 = i4 / CAP_G, g5 = i5 / CAP_G, g6 = i6 / CAP_G, g7 = i7 / CAP_G;
            if (i0 - g0 * CAP_G >= lp[g0]) pa = make_int2(0, 0);
            if (i1 - g1 * CAP_G >= lp[g1]) pb = make_int2(0, 0);
            if (i2 - g2 * CAP_G >= lp[g2]) pc = make_int2(0, 0);
            if (i3 - g3 * CAP_G >= lp[g3]) pd = make_int2(0, 0);
            if (i4 - g4 * CAP_G >= lp[g4]) pe = make_int2(0, 0);
            if (i5 - g5 * CAP_G >= lp[g5]) pf = make_int2(0, 0);
            if (i6 - g6 * CAP_G >= lp[g6]) pg = make_int2(0, 0);
            if (i7 - g7 * CAP_G >= lp[g7]) ph = make_int2(0, 0);
            float4 va = *(const float4*)(h + pa.x * 64 + q * 4);
            float4 vb = *(const float4*)(h + pb.x * 64 + q * 4);
            float4 vc = *(const float4*)(h + pc.x * 64 + q * 4);
            float4 vd = *(const float4*)(h + pd.x * 64 + q * 4);
            float4 ve = *(const float4*)(h + pe.x * 64 + q * 4);
            float4 vf = *(const float4*)(h + pf.x * 64 + q * 4);
            float4 vg = *(const float4*)(h + pg.x * 64 + q * 4);
            float4 vh = *(const float4*)(h + ph.x * 64 + q * 4);
            float wa = __int_as_float(pa.y), wb = __int_as_float(pb.y);
            float wc = __int_as_float(pc.y), wd = __int_as_float(pd.y);
            float we = __int_as_float(pe.y), wf = __int_as_float(pf.y);
            float wg = __int_as_float(pg.y), wh = __int_as_float(ph.y);
            acc4.x = fmaf(va.x, wa, acc4.x); acc4.y = fmaf(va.y, wa, acc4.y);
            acc4.z = fmaf(va.z, wa, acc4.z); acc4.w = fmaf(va.w, wa, acc4.w);
            acc4.x = fmaf(vb.x, wb, acc4.x); acc4.y = fmaf(vb.y, wb, acc4.y);
            acc4.z = fmaf(vb.z, wb, acc4.z); acc4.w = fmaf(vb.w, wb, acc4.w);
            acc4.x = fmaf(vc.x, wc, acc4.x); acc4.y = fmaf(vc.y, wc, acc4.y);
            acc4.z = fmaf(vc.z, wc, acc4.z); acc4.w = fmaf(vc.w, wc, acc4.w);
            acc4.x = fmaf(vd.x, wd, acc4.x); acc4.y = fmaf(vd.y, wd, acc4.y);
            acc4.z = fmaf(vd.z, wd, acc4.z); acc4.w = fmaf(vd.w, wd, acc4.w);
            acc4.x = fmaf(ve.x, we, acc4.x); acc4.y = fmaf(ve.y, we, acc4.y);
            acc4.z = fmaf(ve.z, we, acc4.z); acc4.w = fmaf(ve.w, we, acc4.w);
            acc4.x = fmaf(vf.x, wf, acc4.x); acc4.y = fmaf(vf.y, wf, acc4.y);
            acc4.z = fmaf(vf.z, wf, acc4.z); acc4.w = fmaf(vf.w, wf, acc4.w);
            acc4.x = fmaf(vg.x, wg, acc4.x); acc4.y = fmaf(vg.y, wg, acc4.y);
            acc4.z = fmaf(vg.z, wg, acc4.z); acc4.w = fmaf(vg.w, wg, acc4.w);
            acc4.x = fmaf(vh.x, wh, acc4.x); acc4.y = fmaf(vh.y, wh, acc4.y);
            acc4.z = fmaf(vh.z, wh, acc4.z); acc4.w = fmaf(vh.w, wh, acc4.w);
        }
        acc4.x += __shfl_xor(acc4.x, 16); acc4.y += __shfl_xor(acc4.y, 16);
        acc4.z += __shfl_xor(acc4.z, 16); acc4.w += __shfl_xor(acc4.w, 16);
        acc4.x += __shfl_xor(acc4.x, 32); acc4.y += __shfl_xor(acc4.y, 32);
        acc4.z += __shfl_xor(acc4.z, 32); acc4.w += __shfl_xor(acc4.w, 32);
        if (eslot == 0) *(float4*)(&a2[nn][q * 4]) = acc4;
        hrow[nn][c] = h[n * 64 + c];
        __syncthreads();
        // GEMV: 4 groups of 128 threads; group g computes nodes 2g, 2g+1 over full kk.
        int g = t >> 7, c2 = t & 127;
        if (c2 < NCLUST) {
            int na = 2 * g, nb2 = 2 * g + 1;
            float s0 = b2s[c2], s1 = s0;
#pragma unroll 8
            for (int kk = 0; kk < 64; ++kk) {
                float wr = wsrel[kk * 100 + c2];
                float wo = w2t_root[kk * 100 + c2];
                s0 = fmaf(a2[na][kk], wr, fmaf(hrow[na][kk], wo, s0));
                s1 = fmaf(a2[nb2][kk], wr, fmaf(hrow[nb2][kk], wo, s1));
            }
            logits[na][c2] = s0;
            logits[nb2][c2] = s1;
        }
        __syncthreads();
        float v0 = logits[nn][c];
        float v1 = (c < NCLUST - 64) ? logits[nn][64 + c] : -INFINITY;
        float m = fmaxf(v0, v1);
#pragma unroll
        for (int off = 32; off > 0; off >>= 1) m = fmaxf(m, __shfl_xor(m, off));
        float e0 = __expf(v0 - m);
        float e1 = (c < NCLUST - 64) ? __expf(v1 - m) : 0.f;
        float s = e0 + e1;
#pragma unroll
        for (int off = 32; off > 0; off >>= 1) s += __shfl_xor(s, off);
        float inv = 1.f / s;
        out[n * NCLUST + c] = e0 * inv;
        if (c < NCLUST - 64) out[n * NCLUST + 64 + c] = e1 * inv;
    } else {
        // ---- scalars mc, o (512 threads; entries live in t<256)
        float* red = wsrel;
        float sv = 0.f;
        if (t < 256)
            for (int bb = 0; bb < NBLK_N; ++bb) sv += sspart[bb * 256 + t];
        red[t] = sv * sv;
        __syncthreads();
        for (int s = 256; s > 0; s >>= 1) {
            if (t < s) red[t] += red[t + s];
            __syncthreads();
        }
        float ssnorm = sqrtf(red[0]);
        __syncthreads();
        float diff = (t < 256) ? (sv / ssnorm - ((t % 17 == 0) ? 0.25f : 0.f)) : 0.f;
        red[t] = diff * diff;
        __syncthreads();
        for (int s = 256; s > 0; s >>= 1) {
            if (t < s) red[t] += red[t + s];
            __syncthreads();
        }
        if (t == 0) {
            out[N_NODES * NCLUST + 0] = -(scal[0] / scal[1]);
            out[N_NODES * NCLUST + 1] = sqrtf(red[0]);
        }
    }
}

extern "C" void kernel_launch(void* const* d_in, const int* in_sizes, int n_in,
                              void* d_out, int out_size, void* d_ws, size_t ws_size,
                              hipStream_t stream) {
    const float* x       = (const float*)d_in[0];
    const int*   ei      = (const int*)d_in[1];
    const float* ew      = (const float*)d_in[2];
    const float* W1_rel  = (const float*)d_in[3];
    const float* W1_root = (const float*)d_in[4];
    const float* b1      = (const float*)d_in[5];
    const float* W2_rel  = (const float*)d_in[6];
    const float* W2_root = (const float*)d_in[7];
    const float* b2      = (const float*)d_in[8];
    float* out = (float*)d_out;
    int*   wsi = (int*)d_ws;

    int*   count   = wsi + OFF_COUNT;
    float* scal    = (float*)(wsi + OFF_SCAL);
    float* sspart  = (float*)(wsi + OFF_SSPART);
    float* norm2   = (float*)(wsi + OFF_NORM2);
    float* w2trel  = (float*)(wsi + OFF_W2TREL);
    float* w2troot = (float*)(wsi + OFF_W2TROOT);
    float* smc     = (float*)(wsi + OFF_SMC);
    float* h       = (float*)(wsi + OFF_H);
    int2*  srcw    = (int2*)(wsi + OFF_SRCW);

    hipMemsetAsync(wsi, 0, ZERO_ELEMS * sizeof(int), stream);
    phase0_kernel<<<NBLK_N + NBLK_E + 2, 256, 0, stream>>>(x, ei, ew, smc, norm2, count, srcw,
                                                           W2_rel, W2_root, w2trel, w2troot);
    fused1_pass2_kernel<<<NBLK_F1 + NBLK_N + NBLK_E, 256, 0, stream>>>(
        x, srcw, count, W1_rel, W1_root, b1, h, smc, sspart, ei, ew, norm2, scal);
    fused2_finalize_kernel<<<NBLK_F2 + 1, 512, 0, stream>>>(h, srcw, count, w2trel, w2troot,
                                                            b2, out, sspart, scal);
}

// Round 15
// 102.003 us; speedup vs baseline: 1.1970x; 1.1970x over previous
//
#include <hip/hip_runtime.h>
#include <math.h>

#define N_NODES 12000
#define F_INN 16
#define HIDD 64
#define NCLUST 100
#define NEDGE 384000
#define NBLK_N 47          // ceil(12000/256)
#define CAP 96             // bucket capacity per node (deg: mu=32, sigma=5.7)
#define EPT 4              // edges per thread in edge passes
#define NSTRIPE 8          // destination stripes; stripe s handled by blocks with b%8==s (~XCD)
#define SPAN 1500          // nodes per stripe (12000/8)
#define NBLK_C 375         // edge chunks (NEDGE/EPT/256)
#define NBLK_FILL (NSTRIPE * NBLK_C)   // 3000 fill blocks
#define NBLK_E 375         // mincut blocks (EPT=4, 256 thr)
#define NBLK_F1 (N_NODES / 4)          // 3000 (4 nodes/block, 256 threads)
#define NBLK_F2 (N_NODES / 8)          // 1500 (8 nodes/block, 512 threads)

// ws layout (4-byte element offsets) — identical to r11:
#define OFF_COUNT   0        // 12000 int  (memset each call)
#define OFF_SCAL    12000    // 2 f32      (memset each call)
#define ZERO_ELEMS  12002
#define OFF_SSPART  12004    // 47*256 = 12032 f32
#define OFF_NORM2   24036    // 12000 f32
#define OFF_W2TREL  36036    // 6400 f32  (W2_rel transposed [64][100])
#define OFF_W2TROOT 42436    // 6400 f32
#define OFF_SMC     48836    // 192000 f32
#define OFF_H       240836   // 768000 f32
#define OFF_SRCW    1008836  // 12000*96 int2 (byte off 4035344, 8B aligned)

// ---------------- phase0: striped bucket-fill | smc softmax+norm2 | W2 transpose
// Fill: block b -> stripe b&7, chunk b>>3. Only edges with d in stripe are kept, so all
// atomics/stores for a node issue from one XCD (blockIdx%8 round-robin) -> lines merge
// in that L2 and write back once. Bucket layout/gather identical to r11.
__global__ void phase0_kernel(const float* __restrict__ x, const int* __restrict__ ei,
                              const float* __restrict__ ew, float* __restrict__ smc,
                              float* __restrict__ norm2, int* __restrict__ count,
                              int2* __restrict__ srcw, const float* __restrict__ W2_rel,
                              const float* __restrict__ W2_root, float* __restrict__ w2t_rel,
                              float* __restrict__ w2t_root) {
    __shared__ float fl[6400];
    int t = threadIdx.x;
    int b = blockIdx.x;
    if (b < NBLK_FILL) {
        int stripe = b & (NSTRIPE - 1);
        int chunk = b >> 3;
        int tid = chunk * 256 + t;
        int e0 = tid * EPT;
        int4 sv = *(const int4*)(ei + e0);
        int4 dv = *(const int4*)(ei + NEDGE + e0);
        float4 wv = *(const float4*)(ew + e0);
        int s[EPT] = {sv.x, sv.y, sv.z, sv.w};
        int d[EPT] = {dv.x, dv.y, dv.z, dv.w};
        float w[EPT] = {wv.x, wv.y, wv.z, wv.w};
#pragma unroll
        for (int i = 0; i < EPT; ++i) {
            if (d[i] / SPAN == stripe) {
                int pos = atomicAdd(&count[d[i]], 1);
                srcw[d[i] * CAP + pos] = make_int2(s[i], __float_as_int(w[i]));
            }
        }
    } else if (b < NBLK_FILL + NBLK_N) {
        int i = (b - NBLK_FILL) * 256 + t;
        if (i >= N_NODES) return;
        const float4* xr = (const float4*)(x + i * 16);
        float4 r0 = xr[0], r1 = xr[1], r2 = xr[2], r3 = xr[3];
        float v[16] = {r0.x, r0.y, r0.z, r0.w, r1.x, r1.y, r1.z, r1.w,
                       r2.x, r2.y, r2.z, r2.w, r3.x, r3.y, r3.z, r3.w};
        float m = v[0];
#pragma unroll
        for (int k = 1; k < 16; ++k) m = fmaxf(m, v[k]);
        float s = 0.f;
#pragma unroll
        for (int k = 0; k < 16; ++k) { v[k] = __expf(v[k] - m); s += v[k]; }
        float inv = 1.f / s;
        float n2 = 0.f;
#pragma unroll
        for (int k = 0; k < 16; ++k) { v[k] *= inv; n2 += v[k] * v[k]; }
        float4* so = (float4*)(smc + i * 16);
        so[0] = make_float4(v[0], v[1], v[2], v[3]);
        so[1] = make_float4(v[4], v[5], v[6], v[7]);
        so[2] = make_float4(v[8], v[9], v[10], v[11]);
        so[3] = make_float4(v[12], v[13], v[14], v[15]);
        norm2[i] = n2;
    } else {
        const float* src = (b == NBLK_FILL + NBLK_N) ? W2_rel : W2_root;
        float* dst = (b == NBLK_FILL + NBLK_N) ? w2t_rel : w2t_root;
        for (int i = t; i < 6400; i += 256) fl[i] = src[i];
        __syncthreads();
        for (int j = t; j < 6400; j += 256) {
            int kk = j / 100, cl = j - kk * 100;
            dst[j] = fl[cl * 64 + kk];
        }
    }
}

// ---------------- merged: fused layer 1 | ss partials | mincut edge reduction  (r11 exact)
__global__ void fused1_pass2_kernel(const float* __restrict__ x, const int2* __restrict__ srcw,
                                    const int* __restrict__ count, const float* __restrict__ W1_rel,
                                    const float* __restrict__ W1_root, const float* __restrict__ b1,
                                    float* __restrict__ h, const float* __restrict__ smc,
                                    float* __restrict__ sspart, const int* __restrict__ ei,
                                    const float* __restrict__ ew, const float* __restrict__ norm2,
                                    float* __restrict__ scal) {
    __shared__ float shm[4352];
    int t = threadIdx.x;
    int b = blockIdx.x;
    if (b < NBLK_F1) {
        float* wrelT  = shm;          // 16*64
        float* wrootT = shm + 1024;   // 16*64
        float* b1s    = shm + 2048;   // 64
        float* aggr   = shm + 2112;   // [4][16]
        float* xs     = shm + 2176;   // [4][16]
        for (int idx = t; idx < 1024; idx += 256) {
            int f = idx >> 4, k = idx & 15;
            wrelT[(k << 6) + f]  = W1_rel[idx];
            wrootT[(k << 6) + f] = W1_root[idx];
        }
        if (t < 64) b1s[t] = b1[t];
        int w = t >> 6, lane = t & 63;
        int j2 = lane >> 2;   // edge slot 0..15
        int q  = lane & 3;    // float4 chunk of the 16-float x row
        int n = b * 4 + w;
        int len = count[n];
        const int2* bucket = srcw + n * CAP;
        float4 acc4 = make_float4(0.f, 0.f, 0.f, 0.f);
        for (int k = 0; k < len; k += 32) {   // predicated full-width batches
            int ia = k + j2, ib = k + 16 + j2;
            int2 pa = bucket[ia];
            int2 pb = bucket[ib];
            if (ia >= len) pa = make_int2(0, 0);   // w=0 -> fma is identity
            if (ib >= len) pb = make_int2(0, 0);
            float4 va = *(const float4*)(x + pa.x * 16 + q * 4);
            float4 vb = *(const float4*)(x + pb.x * 16 + q * 4);
            float wa = __int_as_float(pa.y), wb = __int_as_float(pb.y);
            acc4.x = fmaf(va.x, wa, acc4.x); acc4.y = fmaf(va.y, wa, acc4.y);
            acc4.z = fmaf(va.z, wa, acc4.z); acc4.w = fmaf(va.w, wa, acc4.w);
            acc4.x = fmaf(vb.x, wb, acc4.x); acc4.y = fmaf(vb.y, wb, acc4.y);
            acc4.z = fmaf(vb.z, wb, acc4.z); acc4.w = fmaf(vb.w, wb, acc4.w);
        }
        acc4.x += __shfl_xor(acc4.x, 4);  acc4.y += __shfl_xor(acc4.y, 4);
        acc4.z += __shfl_xor(acc4.z, 4);  acc4.w += __shfl_xor(acc4.w, 4);
        acc4.x += __shfl_xor(acc4.x, 8);  acc4.y += __shfl_xor(acc4.y, 8);
        acc4.z += __shfl_xor(acc4.z, 8);  acc4.w += __shfl_xor(acc4.w, 8);
        acc4.x += __shfl_xor(acc4.x, 16); acc4.y += __shfl_xor(acc4.y, 16);
        acc4.z += __shfl_xor(acc4.z, 16); acc4.w += __shfl_xor(acc4.w, 16);
        acc4.x += __shfl_xor(acc4.x, 32); acc4.y += __shfl_xor(acc4.y, 32);
        acc4.z += __shfl_xor(acc4.z, 32); acc4.w += __shfl_xor(acc4.w, 32);
        if (j2 == 0) *(float4*)(aggr + w * 16 + q * 4) = acc4;
        if (lane < 16) xs[w * 16 + lane] = x[n * 16 + lane];
        __syncthreads();
        float o = b1s[lane];
#pragma unroll
        for (int kk = 0; kk < 16; ++kk)
            o = fmaf(aggr[w * 16 + kk], wrelT[(kk << 6) + lane],
                     fmaf(xs[w * 16 + kk], wrootT[(kk << 6) + lane], o));
        h[n * 64 + lane] = fmaxf(o, 0.f);
    } else if (b < NBLK_F1 + NBLK_N) {
        int bb = b - NBLK_F1;
        float* rows = shm;            // 256*17
        int n = bb * 256 + t;
        float* rp = rows + t * 17;
        if (n < N_NODES) {
            const float4* sr = (const float4*)(smc + n * 16);
            float4 a0 = sr[0], a1 = sr[1], a2v = sr[2], a3 = sr[3];
            rp[0] = a0.x;  rp[1] = a0.y;  rp[2] = a0.z;  rp[3] = a0.w;
            rp[4] = a1.x;  rp[5] = a1.y;  rp[6] = a1.z;  rp[7] = a1.w;
            rp[8] = a2v.x; rp[9] = a2v.y; rp[10] = a2v.z; rp[11] = a2v.w;
            rp[12] = a3.x; rp[13] = a3.y; rp[14] = a3.z; rp[15] = a3.w;
        } else {
#pragma unroll
            for (int k = 0; k < 16; ++k) rp[k] = 0.f;
        }
        __syncthreads();
        int a = t & 15, bq = t >> 4;
        float accs = 0.f;
#pragma unroll 4
        for (int r = 0; r < 256; ++r)
            accs = fmaf(rows[r * 17 + a], rows[r * 17 + bq], accs);
        sspart[bb * 256 + t] = accs;
    } else {
        int tid = (b - NBLK_F1 - NBLK_N) * 256 + t;
        int e0 = tid * EPT;
        int4 sv = *(const int4*)(ei + e0);
        int4 dv = *(const int4*)(ei + NEDGE + e0);
        float4 wv = *(const float4*)(ew + e0);
        int s[EPT] = {sv.x, sv.y, sv.z, sv.w};
        int d[EPT] = {dv.x, dv.y, dv.z, dv.w};
        float w[EPT] = {wv.x, wv.y, wv.z, wv.w};
        float np = 0.f, dp = 0.f;
#pragma unroll
        for (int i = 0; i < EPT; ++i) {
            const float4* ps = (const float4*)(smc + s[i] * 16);
            const float4* pd = (const float4*)(smc + d[i] * 16);
            float4 s0 = ps[0], s1 = ps[1], s2 = ps[2], s3 = ps[3];
            float4 d0 = pd[0], d1 = pd[1], d2 = pd[2], d3 = pd[3];
            float dot = s0.x * d0.x + s0.y * d0.y + s0.z * d0.z + s0.w * d0.w +
                        s1.x * d1.x + s1.y * d1.y + s1.z * d1.z + s1.w * d1.w +
                        s2.x * d2.x + s2.y * d2.y + s2.z * d2.z + s2.w * d2.w +
                        s3.x * d3.x + s3.y * d3.y + s3.z * d3.z + s3.w * d3.w;
            np = fmaf(w[i], dot, np);
            dp = fmaf(w[i], norm2[s[i]], dp);
        }
        float* redn = shm;
        float* redd = shm + 256;
        redn[t] = np;
        redd[t] = dp;
        __syncthreads();
        for (int s2 = 128; s2 > 0; s2 >>= 1) {
            if (t < s2) { redn[t] += redn[t + s2]; redd[t] += redd[t + s2]; }
            __syncthreads();
        }
        if (t == 0) {
            atomicAdd(&scal[0], redn[0]);
            atomicAdd(&scal[1], redd[0]);
        }
    }
}

// ---------------- merged: fused layer 2 (8 nodes/block, W2_rel staged in LDS) | finalize (r11 exact)
__global__ __launch_bounds__(512) void fused2_finalize_kernel(
    const float* __restrict__ h, const int2* __restrict__ srcw, const int* __restrict__ count,
    const float* __restrict__ w2t_rel, const float* __restrict__ w2t_root,
    const float* __restrict__ b2, float* __restrict__ out, const float* __restrict__ sspart,
    const float* __restrict__ scal) {
    __shared__ float wsrel[6400];   // w2t_rel staged (25.6 KB); finalize reuses as red[]
    __shared__ float a2[8][64], hrow[8][64];
    __shared__ float logits[8][104];
    __shared__ float b2s[104];
    int t = threadIdx.x;
    int b = blockIdx.x;
    if (b < NBLK_F2) {
        for (int i = t; i < 6400; i += 512) wsrel[i] = w2t_rel[i];
        if (t < NCLUST) b2s[t] = b2[t];
        int nn = t >> 6;            // wave id = node slot 0..7
        int c = t & 63;
        int eslot = c >> 4;         // edge slot 0..3
        int q = c & 15;             // float4 chunk of the 64-float h row
        int n = b * 8 + nn;
        int len = count[n];
        const int2* bucket = srcw + n * CAP;
        float4 acc4 = make_float4(0.f, 0.f, 0.f, 0.f);
        for (int k = 0; k < len; k += 32) {   // predicated full-width batches
            int i0 = k + eslot,      i1 = k + 4 + eslot;
            int i2 = k + 8 + eslot,  i3 = k + 12 + eslot;
            int i4 = k + 16 + eslot, i5 = k + 20 + eslot;
            int i6 = k + 24 + eslot, i7 = k + 28 + eslot;
            int2 pa = bucket[i0]; int2 pb = bucket[i1];
            int2 pc = bucket[i2]; int2 pd = bucket[i3];
            int2 pe = bucket[i4]; int2 pf = bucket[i5];
            int2 pg = bucket[i6]; int2 ph = bucket[i7];
            if (i0 >= len) pa = make_int2(0, 0);   // w=0 -> fma is identity
            if (i1 >= len) pb = make_int2(0, 0);
            if (i2 >= len) pc = make_int2(0, 0);
            if (i3 >= len) pd = make_int2(0, 0);
            if (i4 >= len) pe = make_int2(0, 0);
            if (i5 >= len) pf = make_int2(0, 0);
            if (i6 >= len) pg = make_int2(0, 0);
            if (i7 >= len) ph = make_int2(0, 0);
            float4 va = *(const float4*)(h + pa.x * 64 + q * 4);
            float4 vb = *(const float4*)(h + pb.x * 64 + q * 4);
            float4 vc = *(const float4*)(h + pc.x * 64 + q * 4);
            float4 vd = *(const float4*)(h + pd.x * 64 + q * 4);
            float4 ve = *(const float4*)(h + pe.x * 64 + q * 4);
            float4 vf = *(const float4*)(h + pf.x * 64 + q * 4);
            float4 vg = *(const float4*)(h + pg.x * 64 + q * 4);
            float4 vh = *(const float4*)(h + ph.x * 64 + q * 4);
            float wa = __int_as_float(pa.y), wb = __int_as_float(pb.y);
            float wc = __int_as_float(pc.y), wd = __int_as_float(pd.y);
            float we = __int_as_float(pe.y), wf = __int_as_float(pf.y);
            float wg = __int_as_float(pg.y), wh = __int_as_float(ph.y);
            acc4.x = fmaf(va.x, wa, acc4.x); acc4.y = fmaf(va.y, wa, acc4.y);
            acc4.z = fmaf(va.z, wa, acc4.z); acc4.w = fmaf(va.w, wa, acc4.w);
            acc4.x = fmaf(vb.x, wb, acc4.x); acc4.y = fmaf(vb.y, wb, acc4.y);
            acc4.z = fmaf(vb.z, wb, acc4.z); acc4.w = fmaf(vb.w, wb, acc4.w);
            acc4.x = fmaf(vc.x, wc, acc4.x); acc4.y = fmaf(vc.y, wc, acc4.y);
            acc4.z = fmaf(vc.z, wc, acc4.z); acc4.w = fmaf(vc.w, wc, acc4.w);
            acc4.x = fmaf(vd.x, wd, acc4.x); acc4.y = fmaf(vd.y, wd, acc4.y);
            acc4.z = fmaf(vd.z, wd, acc4.z); acc4.w = fmaf(vd.w, wd, acc4.w);
            acc4.x = fmaf(ve.x, we, acc4.x); acc4.y = fmaf(ve.y, we, acc4.y);
            acc4.z = fmaf(ve.z, we, acc4.z); acc4.w = fmaf(ve.w, we, acc4.w);
            acc4.x = fmaf(vf.x, wf, acc4.x); acc4.y = fmaf(vf.y, wf, acc4.y);
            acc4.z = fmaf(vf.z, wf, acc4.z); acc4.w = fmaf(vf.w, wf, acc4.w);
            acc4.x = fmaf(vg.x, wg, acc4.x); acc4.y = fmaf(vg.y, wg, acc4.y);
            acc4.z = fmaf(vg.z, wg, acc4.z); acc4.w = fmaf(vg.w, wg, acc4.w);
            acc4.x = fmaf(vh.x, wh, acc4.x); acc4.y = fmaf(vh.y, wh, acc4.y);
            acc4.z = fmaf(vh.z, wh, acc4.z); acc4.w = fmaf(vh.w, wh, acc4.w);
        }
        acc4.x += __shfl_xor(acc4.x, 16); acc4.y += __shfl_xor(acc4.y, 16);
        acc4.z += __shfl_xor(acc4.z, 16); acc4.w += __shfl_xor(acc4.w, 16);
        acc4.x += __shfl_xor(acc4.x, 32); acc4.y += __shfl_xor(acc4.y, 32);
        acc4.z += __shfl_xor(acc4.z, 32); acc4.w += __shfl_xor(acc4.w, 32);
        if (eslot == 0) *(float4*)(&a2[nn][q * 4]) = acc4;
        hrow[nn][c] = h[n * 64 + c];
        __syncthreads();
        // GEMV: 4 groups of 128 threads; group g computes nodes 2g, 2g+1 over full kk.
        int g = t >> 7, c2 = t & 127;
        if (c2 < NCLUST) {
            int na = 2 * g, nb2 = 2 * g + 1;
            float s0 = b2s[c2], s1 = s0;
#pragma unroll 8
            for (int kk = 0; kk < 64; ++kk) {
                float wr = wsrel[kk * 100 + c2];
                float wo = w2t_root[kk * 100 + c2];
                s0 = fmaf(a2[na][kk], wr, fmaf(hrow[na][kk], wo, s0));
                s1 = fmaf(a2[nb2][kk], wr, fmaf(hrow[nb2][kk], wo, s1));
            }
            logits[na][c2] = s0;
            logits[nb2][c2] = s1;
        }
        __syncthreads();
        float v0 = logits[nn][c];
        float v1 = (c < NCLUST - 64) ? logits[nn][64 + c] : -INFINITY;
        float m = fmaxf(v0, v1);
#pragma unroll
        for (int off = 32; off > 0; off >>= 1) m = fmaxf(m, __shfl_xor(m, off));
        float e0 = __expf(v0 - m);
        float e1 = (c < NCLUST - 64) ? __expf(v1 - m) : 0.f;
        float s = e0 + e1;
#pragma unroll
        for (int off = 32; off > 0; off >>= 1) s += __shfl_xor(s, off);
        float inv = 1.f / s;
        out[n * NCLUST + c] = e0 * inv;
        if (c < NCLUST - 64) out[n * NCLUST + 64 + c] = e1 * inv;
    } else {
        // ---- scalars mc, o (512 threads; entries live in t<256)
        float* red = wsrel;
        float sv = 0.f;
        if (t < 256)
            for (int bb = 0; bb < NBLK_N; ++bb) sv += sspart[bb * 256 + t];
        red[t] = sv * sv;
        __syncthreads();
        for (int s = 256; s > 0; s >>= 1) {
            if (t < s) red[t] += red[t + s];
            __syncthreads();
        }
        float ssnorm = sqrtf(red[0]);
        __syncthreads();
        float diff = (t < 256) ? (sv / ssnorm - ((t % 17 == 0) ? 0.25f : 0.f)) : 0.f;
        red[t] = diff * diff;
        __syncthreads();
        for (int s = 256; s > 0; s >>= 1) {
            if (t < s) red[t] += red[t + s];
            __syncthreads();
        }
        if (t == 0) {
            out[N_NODES * NCLUST + 0] = -(scal[0] / scal[1]);
            out[N_NODES * NCLUST + 1] = sqrtf(red[0]);
        }
    }
}

extern "C" void kernel_launch(void* const* d_in, const int* in_sizes, int n_in,
                              void* d_out, int out_size, void* d_ws, size_t ws_size,
                              hipStream_t stream) {
    const float* x       = (const float*)d_in[0];
    const int*   ei      = (const int*)d_in[1];
    const float* ew      = (const float*)d_in[2];
    const float* W1_rel  = (const float*)d_in[3];
    const float* W1_root = (const float*)d_in[4];
    const float* b1      = (const float*)d_in[5];
    const float* W2_rel  = (const float*)d_in[6];
    const float* W2_root = (const float*)d_in[7];
    const float* b2      = (const float*)d_in[8];
    float* out = (float*)d_out;
    int*   wsi = (int*)d_ws;

    int*   count   = wsi + OFF_COUNT;
    float* scal    = (float*)(wsi + OFF_SCAL);
    float* sspart  = (float*)(wsi + OFF_SSPART);
    float* norm2   = (float*)(wsi + OFF_NORM2);
    float* w2trel  = (float*)(wsi + OFF_W2TREL);
    float* w2troot = (float*)(wsi + OFF_W2TROOT);
    float* smc     = (float*)(wsi + OFF_SMC);
    float* h       = (float*)(wsi + OFF_H);
    int2*  srcw    = (int2*)(wsi + OFF_SRCW);

    hipMemsetAsync(wsi, 0, ZERO_ELEMS * sizeof(int), stream);
    phase0_kernel<<<NBLK_FILL + NBLK_N + 2, 256, 0, stream>>>(x, ei, ew, smc, norm2, count, srcw,
                                                              W2_rel, W2_root, w2trel, w2troot);
    fused1_pass2_kernel<<<NBLK_F1 + NBLK_N + NBLK_E, 256, 0, stream>>>(
        x, srcw, count, W1_rel, W1_root, b1, h, smc, sspart, ei, ew, norm2, scal);
    fused2_finalize_kernel<<<NBLK_F2 + 1, 512, 0, stream>>>(h, srcw, count, w2trel, w2troot,
                                                            b2, out, sspart, scal);
}

// Round 16
// 99.371 us; speedup vs baseline: 1.2287x; 1.0265x over previous
//
#include <hip/hip_runtime.h>
#include <math.h>

#define N_NODES 12000
#define F_INN 16
#define HIDD 64
#define NCLUST 100
#define NEDGE 384000
#define NBLK_N 47          // ceil(12000/256)
#define CAP 96             // bucket capacity per node (deg: mu=32, sigma=5.7)
#define EPT 4              // edges per thread in edge passes
#define NBLK_E 375         // (NEDGE/EPT)/256
#define NBLK_F1 (N_NODES / 4)          // 3000 (4 nodes/block, 256 threads)
#define NBLK_F2 (N_NODES / 8)          // 1500 (8 nodes/block, 512 threads)

// ws layout (4-byte element offsets) — identical to r11:
#define OFF_COUNT   0        // 12000 int  (memset each call)
#define OFF_SCAL    12000    // 2 f32      (memset each call)
#define ZERO_ELEMS  12002
#define OFF_SSPART  12004    // 47*256 = 12032 f32
#define OFF_NORM2   24036    // 12000 f32
#define OFF_W2TREL  36036    // 6400 f32  (W2_rel transposed [64][100])
#define OFF_W2TROOT 42436    // 6400 f32
#define OFF_SMC     48836    // 192000 f32
#define OFF_H       240836   // 768000 f32
#define OFF_SRCW    1008836  // 12000*96 int2 (byte off 4035344, 8B aligned)

// ---------------- pre: smc softmax+norm2 | W2 transpose (small, feeds scatter launch)
__global__ void pre_kernel(const float* __restrict__ x, float* __restrict__ smc,
                           float* __restrict__ norm2, const float* __restrict__ W2_rel,
                           const float* __restrict__ W2_root, float* __restrict__ w2t_rel,
                           float* __restrict__ w2t_root) {
    __shared__ float fl[6400];
    int t = threadIdx.x;
    int b = blockIdx.x;
    if (b < NBLK_N) {
        int i = b * 256 + t;
        if (i >= N_NODES) return;
        const float4* xr = (const float4*)(x + i * 16);
        float4 r0 = xr[0], r1 = xr[1], r2 = xr[2], r3 = xr[3];
        float v[16] = {r0.x, r0.y, r0.z, r0.w, r1.x, r1.y, r1.z, r1.w,
                       r2.x, r2.y, r2.z, r2.w, r3.x, r3.y, r3.z, r3.w};
        float m = v[0];
#pragma unroll
        for (int k = 1; k < 16; ++k) m = fmaxf(m, v[k]);
        float s = 0.f;
#pragma unroll
        for (int k = 0; k < 16; ++k) { v[k] = __expf(v[k] - m); s += v[k]; }
        float inv = 1.f / s;
        float n2 = 0.f;
#pragma unroll
        for (int k = 0; k < 16; ++k) { v[k] *= inv; n2 += v[k] * v[k]; }
        float4* so = (float4*)(smc + i * 16);
        so[0] = make_float4(v[0], v[1], v[2], v[3]);
        so[1] = make_float4(v[4], v[5], v[6], v[7]);
        so[2] = make_float4(v[8], v[9], v[10], v[11]);
        so[3] = make_float4(v[12], v[13], v[14], v[15]);
        norm2[i] = n2;
    } else {
        const float* src = (b == NBLK_N) ? W2_rel : W2_root;
        float* dst = (b == NBLK_N) ? w2t_rel : w2t_root;
        for (int i = t; i < 6400; i += 256) fl[i] = src[i];
        __syncthreads();
        for (int j = t; j < 6400; j += 256) {
            int kk = j / 100, cl = j - kk * 100;
            dst[j] = fl[cl * 64 + kk];
        }
    }
}

// ---------------- scatter launch: bucket-fill (latency-bound, VALU ~0.5%) overlapped
// with ss partials + mincut (VALU-bound, depend only on pre outputs) — resource-complementary.
__global__ void scatter_kernel(const int* __restrict__ ei, const float* __restrict__ ew,
                               int* __restrict__ count, int2* __restrict__ srcw,
                               const float* __restrict__ smc, float* __restrict__ sspart,
                               const float* __restrict__ norm2, float* __restrict__ scal) {
    __shared__ float shm[4352];
    int t = threadIdx.x;
    int b = blockIdx.x;
    if (b < NBLK_E) {
        // bucket fill — r11 exact (EPT=4, 375 blocks)
        int tid = b * 256 + t;
        int e0 = tid * EPT;
        int4 sv = *(const int4*)(ei + e0);
        int4 dv = *(const int4*)(ei + NEDGE + e0);
        float4 wv = *(const float4*)(ew + e0);
        int s[EPT] = {sv.x, sv.y, sv.z, sv.w};
        int d[EPT] = {dv.x, dv.y, dv.z, dv.w};
        float w[EPT] = {wv.x, wv.y, wv.z, wv.w};
        int pos[EPT];
#pragma unroll
        for (int i = 0; i < EPT; ++i) pos[i] = atomicAdd(&count[d[i]], 1);
#pragma unroll
        for (int i = 0; i < EPT; ++i)
            srcw[d[i] * CAP + pos[i]] = make_int2(s[i], __float_as_int(w[i]));
    } else if (b < NBLK_E + NBLK_N) {
        // ss partials (S^T S) — r11 exact
        int bb = b - NBLK_E;
        float* rows = shm;            // 256*17
        int n = bb * 256 + t;
        float* rp = rows + t * 17;
        if (n < N_NODES) {
            const float4* sr = (const float4*)(smc + n * 16);
            float4 a0 = sr[0], a1 = sr[1], a2v = sr[2], a3 = sr[3];
            rp[0] = a0.x;  rp[1] = a0.y;  rp[2] = a0.z;  rp[3] = a0.w;
            rp[4] = a1.x;  rp[5] = a1.y;  rp[6] = a1.z;  rp[7] = a1.w;
            rp[8] = a2v.x; rp[9] = a2v.y; rp[10] = a2v.z; rp[11] = a2v.w;
            rp[12] = a3.x; rp[13] = a3.y; rp[14] = a3.z; rp[15] = a3.w;
        } else {
#pragma unroll
            for (int k = 0; k < 16; ++k) rp[k] = 0.f;
        }
        __syncthreads();
        int a = t & 15, bq = t >> 4;
        float accs = 0.f;
#pragma unroll 4
        for (int r = 0; r < 256; ++r)
            accs = fmaf(rows[r * 17 + a], rows[r * 17 + bq], accs);
        sspart[bb * 256 + t] = accs;
    } else {
        // mincut num/den edge reduction — r11 exact
        int tid = (b - NBLK_E - NBLK_N) * 256 + t;
        int e0 = tid * EPT;
        int4 sv = *(const int4*)(ei + e0);
        int4 dv = *(const int4*)(ei + NEDGE + e0);
        float4 wv = *(const float4*)(ew + e0);
        int s[EPT] = {sv.x, sv.y, sv.z, sv.w};
        int d[EPT] = {dv.x, dv.y, dv.z, dv.w};
        float w[EPT] = {wv.x, wv.y, wv.z, wv.w};
        float np = 0.f, dp = 0.f;
#pragma unroll
        for (int i = 0; i < EPT; ++i) {
            const float4* ps = (const float4*)(smc + s[i] * 16);
            const float4* pd = (const float4*)(smc + d[i] * 16);
            float4 s0 = ps[0], s1 = ps[1], s2 = ps[2], s3 = ps[3];
            float4 d0 = pd[0], d1 = pd[1], d2 = pd[2], d3 = pd[3];
            float dot = s0.x * d0.x + s0.y * d0.y + s0.z * d0.z + s0.w * d0.w +
                        s1.x * d1.x + s1.y * d1.y + s1.z * d1.z + s1.w * d1.w +
                        s2.x * d2.x + s2.y * d2.y + s2.z * d2.z + s2.w * d2.w +
                        s3.x * d3.x + s3.y * d3.y + s3.z * d3.z + s3.w * d3.w;
            np = fmaf(w[i], dot, np);
            dp = fmaf(w[i], norm2[s[i]], dp);
        }
        float* redn = shm;
        float* redd = shm + 256;
        redn[t] = np;
        redd[t] = dp;
        __syncthreads();
        for (int s2 = 128; s2 > 0; s2 >>= 1) {
            if (t < s2) { redn[t] += redn[t + s2]; redd[t] += redd[t + s2]; }
            __syncthreads();
        }
        if (t == 0) {
            atomicAdd(&scal[0], redn[0]);
            atomicAdd(&scal[1], redd[0]);
        }
    }
}

// ---------------- fused layer 1 (pure, tail removed) — body r11 exact
__global__ void fused1_kernel(const float* __restrict__ x, const int2* __restrict__ srcw,
                              const int* __restrict__ count, const float* __restrict__ W1_rel,
                              const float* __restrict__ W1_root, const float* __restrict__ b1,
                              float* __restrict__ h) {
    __shared__ float shm[2304];
    int t = threadIdx.x;
    int b = blockIdx.x;
    float* wrelT  = shm;          // 16*64
    float* wrootT = shm + 1024;   // 16*64
    float* b1s    = shm + 2048;   // 64
    float* aggr   = shm + 2112;   // [4][16]
    float* xs     = shm + 2176;   // [4][16]
    for (int idx = t; idx < 1024; idx += 256) {
        int f = idx >> 4, k = idx & 15;
        wrelT[(k << 6) + f]  = W1_rel[idx];
        wrootT[(k << 6) + f] = W1_root[idx];
    }
    if (t < 64) b1s[t] = b1[t];
    int w = t >> 6, lane = t & 63;
    int j2 = lane >> 2;   // edge slot 0..15
    int q  = lane & 3;    // float4 chunk of the 16-float x row
    int n = b * 4 + w;
    int len = count[n];
    const int2* bucket = srcw + n * CAP;
    float4 acc4 = make_float4(0.f, 0.f, 0.f, 0.f);
    for (int k = 0; k < len; k += 32) {   // predicated full-width batches
        int ia = k + j2, ib = k + 16 + j2;
        int2 pa = bucket[ia];
        int2 pb = bucket[ib];
        if (ia >= len) pa = make_int2(0, 0);   // w=0 -> fma is identity
        if (ib >= len) pb = make_int2(0, 0);
        float4 va = *(const float4*)(x + pa.x * 16 + q * 4);
        float4 vb = *(const float4*)(x + pb.x * 16 + q * 4);
        float wa = __int_as_float(pa.y), wb = __int_as_float(pb.y);
        acc4.x = fmaf(va.x, wa, acc4.x); acc4.y = fmaf(va.y, wa, acc4.y);
        acc4.z = fmaf(va.z, wa, acc4.z); acc4.w = fmaf(va.w, wa, acc4.w);
        acc4.x = fmaf(vb.x, wb, acc4.x); acc4.y = fmaf(vb.y, wb, acc4.y);
        acc4.z = fmaf(vb.z, wb, acc4.z); acc4.w = fmaf(vb.w, wb, acc4.w);
    }
    acc4.x += __shfl_xor(acc4.x, 4);  acc4.y += __shfl_xor(acc4.y, 4);
    acc4.z += __shfl_xor(acc4.z, 4);  acc4.w += __shfl_xor(acc4.w, 4);
    acc4.x += __shfl_xor(acc4.x, 8);  acc4.y += __shfl_xor(acc4.y, 8);
    acc4.z += __shfl_xor(acc4.z, 8);  acc4.w += __shfl_xor(acc4.w, 8);
    acc4.x += __shfl_xor(acc4.x, 16); acc4.y += __shfl_xor(acc4.y, 16);
    acc4.z += __shfl_xor(acc4.z, 16); acc4.w += __shfl_xor(acc4.w, 16);
    acc4.x += __shfl_xor(acc4.x, 32); acc4.y += __shfl_xor(acc4.y, 32);
    acc4.z += __shfl_xor(acc4.z, 32); acc4.w += __shfl_xor(acc4.w, 32);
    if (j2 == 0) *(float4*)(aggr + w * 16 + q * 4) = acc4;
    if (lane < 16) xs[w * 16 + lane] = x[n * 16 + lane];
    __syncthreads();
    float o = b1s[lane];
#pragma unroll
    for (int kk = 0; kk < 16; ++kk)
        o = fmaf(aggr[w * 16 + kk], wrelT[(kk << 6) + lane],
                 fmaf(xs[w * 16 + kk], wrootT[(kk << 6) + lane], o));
    h[n * 64 + lane] = fmaxf(o, 0.f);
}

// ---------------- merged: fused layer 2 (8 nodes/block, W2_rel staged in LDS) | finalize (r11 exact)
__global__ __launch_bounds__(512) void fused2_finalize_kernel(
    const float* __restrict__ h, const int2* __restrict__ srcw, const int* __restrict__ count,
    const float* __restrict__ w2t_rel, const float* __restrict__ w2t_root,
    const float* __restrict__ b2, float* __restrict__ out, const float* __restrict__ sspart,
    const float* __restrict__ scal) {
    __shared__ float wsrel[6400];   // w2t_rel staged (25.6 KB); finalize reuses as red[]
    __shared__ float a2[8][64], hrow[8][64];
    __shared__ float logits[8][104];
    __shared__ float b2s[104];
    int t = threadIdx.x;
    int b = blockIdx.x;
    if (b < NBLK_F2) {
        for (int i = t; i < 6400; i += 512) wsrel[i] = w2t_rel[i];
        if (t < NCLUST) b2s[t] = b2[t];
        int nn = t >> 6;            // wave id = node slot 0..7
        int c = t & 63;
        int eslot = c >> 4;         // edge slot 0..3
        int q = c & 15;             // float4 chunk of the 64-float h row
        int n = b * 8 + nn;
        int len = count[n];
        const int2* bucket = srcw + n * CAP;
        float4 acc4 = make_float4(0.f, 0.f, 0.f, 0.f);
        for (int k = 0; k < len; k += 32) {   // predicated full-width batches
            int i0 = k + eslot,      i1 = k + 4 + eslot;
            int i2 = k + 8 + eslot,  i3 = k + 12 + eslot;
            int i4 = k + 16 + eslot, i5 = k + 20 + eslot;
            int i6 = k + 24 + eslot, i7 = k + 28 + eslot;
            int2 pa = bucket[i0]; int2 pb = bucket[i1];
            int2 pc = bucket[i2]; int2 pd = bucket[i3];
            int2 pe = bucket[i4]; int2 pf = bucket[i5];
            int2 pg = bucket[i6]; int2 ph = bucket[i7];
            if (i0 >= len) pa = make_int2(0, 0);   // w=0 -> fma is identity
            if (i1 >= len) pb = make_int2(0, 0);
            if (i2 >= len) pc = make_int2(0, 0);
            if (i3 >= len) pd = make_int2(0, 0);
            if (i4 >= len) pe = make_int2(0, 0);
            if (i5 >= len) pf = make_int2(0, 0);
            if (i6 >= len) pg = make_int2(0, 0);
            if (i7 >= len) ph = make_int2(0, 0);
            float4 va = *(const float4*)(h + pa.x * 64 + q * 4);
            float4 vb = *(const float4*)(h + pb.x * 64 + q * 4);
            float4 vc = *(const float4*)(h + pc.x * 64 + q * 4);
            float4 vd = *(const float4*)(h + pd.x * 64 + q * 4);
            float4 ve = *(const float4*)(h + pe.x * 64 + q * 4);
            float4 vf = *(const float4*)(h + pf.x * 64 + q * 4);
            float4 vg = *(const float4*)(h + pg.x * 64 + q * 4);
            float4 vh = *(const float4*)(h + ph.x * 64 + q * 4);
            float wa = __int_as_float(pa.y), wb = __int_as_float(pb.y);
            float wc = __int_as_float(pc.y), wd = __int_as_float(pd.y);
            float we = __int_as_float(pe.y), wf = __int_as_float(pf.y);
            float wg = __int_as_float(pg.y), wh = __int_as_float(ph.y);
            acc4.x = fmaf(va.x, wa, acc4.x); acc4.y = fmaf(va.y, wa, acc4.y);
            acc4.z = fmaf(va.z, wa, acc4.z); acc4.w = fmaf(va.w, wa, acc4.w);
            acc4.x = fmaf(vb.x, wb, acc4.x); acc4.y = fmaf(vb.y, wb, acc4.y);
            acc4.z = fmaf(vb.z, wb, acc4.z); acc4.w = fmaf(vb.w, wb, acc4.w);
            acc4.x = fmaf(vc.x, wc, acc4.x); acc4.y = fmaf(vc.y, wc, acc4.y);
            acc4.z = fmaf(vc.z, wc, acc4.z); acc4.w = fmaf(vc.w, wc, acc4.w);
            acc4.x = fmaf(vd.x, wd, acc4.x); acc4.y = fmaf(vd.y, wd, acc4.y);
            acc4.z = fmaf(vd.z, wd, acc4.z); acc4.w = fmaf(vd.w, wd, acc4.w);
            acc4.x = fmaf(ve.x, we, acc4.x); acc4.y = fmaf(ve.y, we, acc4.y);
            acc4.z = fmaf(ve.z, we, acc4.z); acc4.w = fmaf(ve.w, we, acc4.w);
            acc4.x = fmaf(vf.x, wf, acc4.x); acc4.y = fmaf(vf.y, wf, acc4.y);
            acc4.z = fmaf(vf.z, wf, acc4.z); acc4.w = fmaf(vf.w, wf, acc4.w);
            acc4.x = fmaf(vg.x, wg, acc4.x); acc4.y = fmaf(vg.y, wg, acc4.y);
            acc4.z = fmaf(vg.z, wg, acc4.z); acc4.w = fmaf(vg.w, wg, acc4.w);
            acc4.x = fmaf(vh.x, wh, acc4.x); acc4.y = fmaf(vh.y, wh, acc4.y);
            acc4.z = fmaf(vh.z, wh, acc4.z); acc4.w = fmaf(vh.w, wh, acc4.w);
        }
        acc4.x += __shfl_xor(acc4.x, 16); acc4.y += __shfl_xor(acc4.y, 16);
        acc4.z += __shfl_xor(acc4.z, 16); acc4.w += __shfl_xor(acc4.w, 16);
        acc4.x += __shfl_xor(acc4.x, 32); acc4.y += __shfl_xor(acc4.y, 32);
        acc4.z += __shfl_xor(acc4.z, 32); acc4.w += __shfl_xor(acc4.w, 32);
        if (eslot == 0) *(float4*)(&a2[nn][q * 4]) = acc4;
        hrow[nn][c] = h[n * 64 + c];
        __syncthreads();
        // GEMV: 4 groups of 128 threads; group g computes nodes 2g, 2g+1 over full kk.
        int g = t >> 7, c2 = t & 127;
        if (c2 < NCLUST) {
            int na = 2 * g, nb2 = 2 * g + 1;
            float s0 = b2s[c2], s1 = s0;
#pragma unroll 8
            for (int kk = 0; kk < 64; ++kk) {
                float wr = wsrel[kk * 100 + c2];
                float wo = w2t_root[kk * 100 + c2];
                s0 = fmaf(a2[na][kk], wr, fmaf(hrow[na][kk], wo, s0));
                s1 = fmaf(a2[nb2][kk], wr, fmaf(hrow[nb2][kk], wo, s1));
            }
            logits[na][c2] = s0;
            logits[nb2][c2] = s1;
        }
        __syncthreads();
        float v0 = logits[nn][c];
        float v1 = (c < NCLUST - 64) ? logits[nn][64 + c] : -INFINITY;
        float m = fmaxf(v0, v1);
#pragma unroll
        for (int off = 32; off > 0; off >>= 1) m = fmaxf(m, __shfl_xor(m, off));
        float e0 = __expf(v0 - m);
        float e1 = (c < NCLUST - 64) ? __expf(v1 - m) : 0.f;
        float s = e0 + e1;
#pragma unroll
        for (int off = 32; off > 0; off >>= 1) s += __shfl_xor(s, off);
        float inv = 1.f / s;
        out[n * NCLUST + c] = e0 * inv;
        if (c < NCLUST - 64) out[n * NCLUST + 64 + c] = e1 * inv;
    } else {
        // ---- scalars mc, o (512 threads; entries live in t<256)
        float* red = wsrel;
        float sv = 0.f;
        if (t < 256)
            for (int bb = 0; bb < NBLK_N; ++bb) sv += sspart[bb * 256 + t];
        red[t] = sv * sv;
        __syncthreads();
        for (int s = 256; s > 0; s >>= 1) {
            if (t < s) red[t] += red[t + s];
            __syncthreads();
        }
        float ssnorm = sqrtf(red[0]);
        __syncthreads();
        float diff = (t < 256) ? (sv / ssnorm - ((t % 17 == 0) ? 0.25f : 0.f)) : 0.f;
        red[t] = diff * diff;
        __syncthreads();
        for (int s = 256; s > 0; s >>= 1) {
            if (t < s) red[t] += red[t + s];
            __syncthreads();
        }
        if (t == 0) {
            out[N_NODES * NCLUST + 0] = -(scal[0] / scal[1]);
            out[N_NODES * NCLUST + 1] = sqrtf(red[0]);
        }
    }
}

extern "C" void kernel_launch(void* const* d_in, const int* in_sizes, int n_in,
                              void* d_out, int out_size, void* d_ws, size_t ws_size,
                              hipStream_t stream) {
    const float* x       = (const float*)d_in[0];
    const int*   ei      = (const int*)d_in[1];
    const float* ew      = (const float*)d_in[2];
    const float* W1_rel  = (const float*)d_in[3];
    const float* W1_root = (const float*)d_in[4];
    const float* b1      = (const float*)d_in[5];
    const float* W2_rel  = (const float*)d_in[6];
    const float* W2_root = (const float*)d_in[7];
    const float* b2      = (const float*)d_in[8];
    float* out = (float*)d_out;
    int*   wsi = (int*)d_ws;

    int*   count   = wsi + OFF_COUNT;
    float* scal    = (float*)(wsi + OFF_SCAL);
    float* sspart  = (float*)(wsi + OFF_SSPART);
    float* norm2   = (float*)(wsi + OFF_NORM2);
    float* w2trel  = (float*)(wsi + OFF_W2TREL);
    float* w2troot = (float*)(wsi + OFF_W2TROOT);
    float* smc     = (float*)(wsi + OFF_SMC);
    float* h       = (float*)(wsi + OFF_H);
    int2*  srcw    = (int2*)(wsi + OFF_SRCW);

    hipMemsetAsync(wsi, 0, ZERO_ELEMS * sizeof(int), stream);
    pre_kernel<<<NBLK_N + 2, 256, 0, stream>>>(x, smc, norm2, W2_rel, W2_root, w2trel, w2troot);
    scatter_kernel<<<NBLK_E + NBLK_N + NBLK_E, 256, 0, stream>>>(ei, ew, count, srcw,
                                                                 smc, sspart, norm2, scal);
    fused1_kernel<<<NBLK_F1, 256, 0, stream>>>(x, srcw, count, W1_rel, W1_root, b1, h);
    fused2_finalize_kernel<<<NBLK_F2 + 1, 512, 0, stream>>>(h, srcw, count, w2trel, w2troot,
                                                            b2, out, sspart, scal);
}

// Round 17
// 90.449 us; speedup vs baseline: 1.3499x; 1.0986x over previous
//
#include <hip/hip_runtime.h>
#include <math.h>

#define N_NODES 12000
#define F_INN 16
#define HIDD 64
#define NCLUST 100
#define NEDGE 384000
#define NBLK_N 47          // ceil(12000/256)
#define CAP 96             // bucket capacity per node (deg: mu=32, sigma=5.7)
#define EPT 4              // edges per thread in edge passes
#define NBLK_E 375         // (NEDGE/EPT)/256
#define NBLK_F1 (N_NODES / 4)          // 3000 (4 nodes/block, 256 threads)
#define NBLK_F2 (N_NODES / 8)          // 1500 (8 nodes/block, 512 threads)

// two-pass binning:
#define NBIN 188           // bins of 64 nodes (bin = dst >> 6); last bin partial
#define BINW 64
#define BCAP 2560          // per-bin capacity (lambda=2043, +11 sigma)
#define STCAP 24           // per-block LDS staging per bin (lambda=5.4, +8 sigma; fallback safe)

// ws layout (4-byte element offsets):
#define OFF_BINCNT  0        // 188 int (memset each call)
#define OFF_SCAL    188      // 2 f32   (memset each call)
#define ZERO_ELEMS  190
#define OFF_COUNT   192      // 12000 int (fully written by bucketize pass)
#define OFF_SSPART  12192    // 12032 f32
#define OFF_NORM2   24224    // 12000 f32
#define OFF_W2TREL  36224    // 6400 f32
#define OFF_W2TROOT 42624    // 6400 f32
#define OFF_SMC     49024    // 192000 f32
#define OFF_H       241024   // 768000 f32
#define OFF_SRCW    1009024  // 12000*96 int2 (byte 4036096, 8B aligned)
#define OFF_BINBUF  3313024  // 188*2560 int2 (byte 13252096, 8B aligned)

// ---------------- pass A: edge binning (LDS-staged appends) | smc softmax+norm2 | W2 transpose
__global__ void binA_kernel(const float* __restrict__ x, const int* __restrict__ ei,
                            const float* __restrict__ ew, float* __restrict__ smc,
                            float* __restrict__ norm2, int* __restrict__ bincnt,
                            int2* __restrict__ binbuf, const float* __restrict__ W2_rel,
                            const float* __restrict__ W2_root, float* __restrict__ w2t_rel,
                            float* __restrict__ w2t_root) {
    __shared__ int shmA[188 + 188 * STCAP * 2];   // scnt[188] + sbuf[188][24] int2 (36.8 KB)
    int t = threadIdx.x;
    int b = blockIdx.x;
    if (b < NBLK_E) {
        int* scnt = shmA;
        int2* sbuf = (int2*)(shmA + 188);
        for (int i = t; i < 188; i += 256) scnt[i] = 0;
        __syncthreads();
        int tid = b * 256 + t;
        int e0 = tid * EPT;
        int4 sv = *(const int4*)(ei + e0);
        int4 dv = *(const int4*)(ei + NEDGE + e0);
        float4 wv = *(const float4*)(ew + e0);
        int s[EPT] = {sv.x, sv.y, sv.z, sv.w};
        int d[EPT] = {dv.x, dv.y, dv.z, dv.w};
        float w[EPT] = {wv.x, wv.y, wv.z, wv.w};
#pragma unroll
        for (int i = 0; i < EPT; ++i) {
            int bin = d[i] >> 6;
            int dl = d[i] & 63;
            int2 rec = make_int2(s[i] | (dl << 16), __float_as_int(w[i]));
            int pos = atomicAdd(&scnt[bin], 1);
            if (pos < STCAP) {
                sbuf[bin * STCAP + pos] = rec;
            } else {                                  // rare overflow: direct global append
                int base = atomicAdd(&bincnt[bin], 1);
                binbuf[bin * BCAP + base] = rec;
            }
        }
        __syncthreads();
        if (t < 188) {                                // flush: thread-per-bin, 1 atomic + ~5 stores
            int k = scnt[t];
            if (k > STCAP) k = STCAP;
            if (k > 0) {
                int base = atomicAdd(&bincnt[t], k);
                for (int i = 0; i < k; ++i) binbuf[t * BCAP + base + i] = sbuf[t * STCAP + i];
            }
        }
    } else if (b < NBLK_E + NBLK_N) {
        int i = (b - NBLK_E) * 256 + t;
        if (i >= N_NODES) return;
        const float4* xr = (const float4*)(x + i * 16);
        float4 r0 = xr[0], r1 = xr[1], r2 = xr[2], r3 = xr[3];
        float v[16] = {r0.x, r0.y, r0.z, r0.w, r1.x, r1.y, r1.z, r1.w,
                       r2.x, r2.y, r2.z, r2.w, r3.x, r3.y, r3.z, r3.w};
        float m = v[0];
#pragma unroll
        for (int k = 1; k < 16; ++k) m = fmaxf(m, v[k]);
        float s = 0.f;
#pragma unroll
        for (int k = 0; k < 16; ++k) { v[k] = __expf(v[k] - m); s += v[k]; }
        float inv = 1.f / s;
        float n2 = 0.f;
#pragma unroll
        for (int k = 0; k < 16; ++k) { v[k] *= inv; n2 += v[k] * v[k]; }
        float4* so = (float4*)(smc + i * 16);
        so[0] = make_float4(v[0], v[1], v[2], v[3]);
        so[1] = make_float4(v[4], v[5], v[6], v[7]);
        so[2] = make_float4(v[8], v[9], v[10], v[11]);
        so[3] = make_float4(v[12], v[13], v[14], v[15]);
        norm2[i] = n2;
    } else {
        float* fl = (float*)shmA;   // 6400 floats fit in shmA
        const float* src = (b == NBLK_E + NBLK_N) ? W2_rel : W2_root;
        float* dst = (b == NBLK_E + NBLK_N) ? w2t_rel : w2t_root;
        for (int i = t; i < 6400; i += 256) fl[i] = src[i];
        __syncthreads();
        for (int j = t; j < 6400; j += 256) {
            int kk = j / 100, cl = j - kk * 100;
            dst[j] = fl[cl * 64 + kk];
        }
    }
}

// ---------------- pass B: per-bin LDS bucketize -> coalesced srcw/count | ss partials | mincut
__global__ void binB_kernel(const int2* __restrict__ binbuf, const int* __restrict__ bincnt,
                            int* __restrict__ count, int2* __restrict__ srcw,
                            const float* __restrict__ smc, float* __restrict__ sspart,
                            const int* __restrict__ ei, const float* __restrict__ ew,
                            const float* __restrict__ norm2, float* __restrict__ scal) {
    __shared__ int shmB[64 + 64 * CAP * 2];   // cnt[64] + lbuck[64][96] int2 (49.4 KB)
    int t = threadIdx.x;
    int b = blockIdx.x;
    if (b < NBIN) {
        int* cnt = shmB;
        int2* lbuck = (int2*)(shmB + 64);
        for (int i = t; i < 64; i += 256) cnt[i] = 0;
        __syncthreads();
        int nE = bincnt[b];
        const int2* bp = binbuf + b * BCAP;
        for (int i = t; i < nE; i += 256) {     // coalesced bin read, LDS-atomic bucketize
            int2 rec = bp[i];
            int src = rec.x & 0xFFFF;
            int dl = rec.x >> 16;
            int pos = atomicAdd(&cnt[dl], 1);
            if (pos < CAP) lbuck[dl * CAP + pos] = make_int2(src, rec.y);
        }
        __syncthreads();
        int nbase = b * BINW;
        int nvalid = N_NODES - nbase;
        if (nvalid > BINW) nvalid = BINW;
        if (t < nvalid) count[nbase + t] = cnt[t];
        int lim = nvalid * CAP;
        int2* out = srcw + (size_t)nbase * CAP;
        for (int i = t; i < lim; i += 256) out[i] = lbuck[i];   // fully coalesced write
    } else if (b < NBIN + NBLK_N) {
        // ---- ss partials (S^T S) — r11 exact
        int bb = b - NBIN;
        float* rows = (float*)shmB;            // 256*17
        int n = bb * 256 + t;
        float* rp = rows + t * 17;
        if (n < N_NODES) {
            const float4* sr = (const float4*)(smc + n * 16);
            float4 a0 = sr[0], a1 = sr[1], a2v = sr[2], a3 = sr[3];
            rp[0] = a0.x;  rp[1] = a0.y;  rp[2] = a0.z;  rp[3] = a0.w;
            rp[4] = a1.x;  rp[5] = a1.y;  rp[6] = a1.z;  rp[7] = a1.w;
            rp[8] = a2v.x; rp[9] = a2v.y; rp[10] = a2v.z; rp[11] = a2v.w;
            rp[12] = a3.x; rp[13] = a3.y; rp[14] = a3.z; rp[15] = a3.w;
        } else {
#pragma unroll
            for (int k = 0; k < 16; ++k) rp[k] = 0.f;
        }
        __syncthreads();
        int a = t & 15, bq = t >> 4;
        float accs = 0.f;
#pragma unroll 4
        for (int r = 0; r < 256; ++r)
            accs = fmaf(rows[r * 17 + a], rows[r * 17 + bq], accs);
        sspart[bb * 256 + t] = accs;
    } else {
        // ---- mincut num/den edge reduction — r11 exact
        int tid = (b - NBIN - NBLK_N) * 256 + t;
        int e0 = tid * EPT;
        int4 sv = *(const int4*)(ei + e0);
        int4 dv = *(const int4*)(ei + NEDGE + e0);
        float4 wv = *(const float4*)(ew + e0);
        int s[EPT] = {sv.x, sv.y, sv.z, sv.w};
        int d[EPT] = {dv.x, dv.y, dv.z, dv.w};
        float w[EPT] = {wv.x, wv.y, wv.z, wv.w};
        float np = 0.f, dp = 0.f;
#pragma unroll
        for (int i = 0; i < EPT; ++i) {
            const float4* ps = (const float4*)(smc + s[i] * 16);
            const float4* pd = (const float4*)(smc + d[i] * 16);
            float4 s0 = ps[0], s1 = ps[1], s2 = ps[2], s3 = ps[3];
            float4 d0 = pd[0], d1 = pd[1], d2 = pd[2], d3 = pd[3];
            float dot = s0.x * d0.x + s0.y * d0.y + s0.z * d0.z + s0.w * d0.w +
                        s1.x * d1.x + s1.y * d1.y + s1.z * d1.z + s1.w * d1.w +
                        s2.x * d2.x + s2.y * d2.y + s2.z * d2.z + s2.w * d2.w +
                        s3.x * d3.x + s3.y * d3.y + s3.z * d3.z + s3.w * d3.w;
            np = fmaf(w[i], dot, np);
            dp = fmaf(w[i], norm2[s[i]], dp);
        }
        float* redn = (float*)shmB;
        float* redd = (float*)shmB + 256;
        redn[t] = np;
        redd[t] = dp;
        __syncthreads();
        for (int s2 = 128; s2 > 0; s2 >>= 1) {
            if (t < s2) { redn[t] += redn[t + s2]; redd[t] += redd[t + s2]; }
            __syncthreads();
        }
        if (t == 0) {
            atomicAdd(&scal[0], redn[0]);
            atomicAdd(&scal[1], redd[0]);
        }
    }
}

// ---------------- fused layer 1 (pure) — r11 body
__global__ void fused1_kernel(const float* __restrict__ x, const int2* __restrict__ srcw,
                              const int* __restrict__ count, const float* __restrict__ W1_rel,
                              const float* __restrict__ W1_root, const float* __restrict__ b1,
                              float* __restrict__ h) {
    __shared__ float shm[2304];
    int t = threadIdx.x;
    int b = blockIdx.x;
    float* wrelT  = shm;          // 16*64
    float* wrootT = shm + 1024;   // 16*64
    float* b1s    = shm + 2048;   // 64
    float* aggr   = shm + 2112;   // [4][16]
    float* xs     = shm + 2176;   // [4][16]
    for (int idx = t; idx < 1024; idx += 256) {
        int f = idx >> 4, k = idx & 15;
        wrelT[(k << 6) + f]  = W1_rel[idx];
        wrootT[(k << 6) + f] = W1_root[idx];
    }
    if (t < 64) b1s[t] = b1[t];
    int w = t >> 6, lane = t & 63;
    int j2 = lane >> 2;   // edge slot 0..15
    int q  = lane & 3;    // float4 chunk of the 16-float x row
    int n = b * 4 + w;
    int len = count[n];
    const int2* bucket = srcw + n * CAP;
    float4 acc4 = make_float4(0.f, 0.f, 0.f, 0.f);
    for (int k = 0; k < len; k += 32) {   // predicated full-width batches
        int ia = k + j2, ib = k + 16 + j2;
        int2 pa = bucket[ia];
        int2 pb = bucket[ib];
        if (ia >= len) pa = make_int2(0, 0);   // w=0 -> fma is identity
        if (ib >= len) pb = make_int2(0, 0);
        float4 va = *(const float4*)(x + pa.x * 16 + q * 4);
        float4 vb = *(const float4*)(x + pb.x * 16 + q * 4);
        float wa = __int_as_float(pa.y), wb = __int_as_float(pb.y);
        acc4.x = fmaf(va.x, wa, acc4.x); acc4.y = fmaf(va.y, wa, acc4.y);
        acc4.z = fmaf(va.z, wa, acc4.z); acc4.w = fmaf(va.w, wa, acc4.w);
        acc4.x = fmaf(vb.x, wb, acc4.x); acc4.y = fmaf(vb.y, wb, acc4.y);
        acc4.z = fmaf(vb.z, wb, acc4.z); acc4.w = fmaf(vb.w, wb, acc4.w);
    }
    acc4.x += __shfl_xor(acc4.x, 4);  acc4.y += __shfl_xor(acc4.y, 4);
    acc4.z += __shfl_xor(acc4.z, 4);  acc4.w += __shfl_xor(acc4.w, 4);
    acc4.x += __shfl_xor(acc4.x, 8);  acc4.y += __shfl_xor(acc4.y, 8);
    acc4.z += __shfl_xor(acc4.z, 8);  acc4.w += __shfl_xor(acc4.w, 8);
    acc4.x += __shfl_xor(acc4.x, 16); acc4.y += __shfl_xor(acc4.y, 16);
    acc4.z += __shfl_xor(acc4.z, 16); acc4.w += __shfl_xor(acc4.w, 16);
    acc4.x += __shfl_xor(acc4.x, 32); acc4.y += __shfl_xor(acc4.y, 32);
    acc4.z += __shfl_xor(acc4.z, 32); acc4.w += __shfl_xor(acc4.w, 32);
    if (j2 == 0) *(float4*)(aggr + w * 16 + q * 4) = acc4;
    if (lane < 16) xs[w * 16 + lane] = x[n * 16 + lane];
    __syncthreads();
    float o = b1s[lane];
#pragma unroll
    for (int kk = 0; kk < 16; ++kk)
        o = fmaf(aggr[w * 16 + kk], wrelT[(kk << 6) + lane],
                 fmaf(xs[w * 16 + kk], wrootT[(kk << 6) + lane], o));
    h[n * 64 + lane] = fmaxf(o, 0.f);
}

// ---------------- merged: fused layer 2 (8 nodes/block, W2_rel staged in LDS) | finalize (r11 exact)
__global__ __launch_bounds__(512) void fused2_finalize_kernel(
    const float* __restrict__ h, const int2* __restrict__ srcw, const int* __restrict__ count,
    const float* __restrict__ w2t_rel, const float* __restrict__ w2t_root,
    const float* __restrict__ b2, float* __restrict__ out, const float* __restrict__ sspart,
    const float* __restrict__ scal) {
    __shared__ float wsrel[6400];   // w2t_rel staged (25.6 KB); finalize reuses as red[]
    __shared__ float a2[8][64], hrow[8][64];
    __shared__ float logits[8][104];
    __shared__ float b2s[104];
    int t = threadIdx.x;
    int b = blockIdx.x;
    if (b < NBLK_F2) {
        for (int i = t; i < 6400; i += 512) wsrel[i] = w2t_rel[i];
        if (t < NCLUST) b2s[t] = b2[t];
        int nn = t >> 6;            // wave id = node slot 0..7
        int c = t & 63;
        int eslot = c >> 4;         // edge slot 0..3
        int q = c & 15;             // float4 chunk of the 64-float h row
        int n = b * 8 + nn;
        int len = count[n];
        const int2* bucket = srcw + n * CAP;
        float4 acc4 = make_float4(0.f, 0.f, 0.f, 0.f);
        for (int k = 0; k < len; k += 32) {   // predicated full-width batches
            int i0 = k + eslot,      i1 = k + 4 + eslot;
            int i2 = k + 8 + eslot,  i3 = k + 12 + eslot;
            int i4 = k + 16 + eslot, i5 = k + 20 + eslot;
            int i6 = k + 24 + eslot, i7 = k + 28 + eslot;
            int2 pa = bucket[i0]; int2 pb = bucket[i1];
            int2 pc = bucket[i2]; int2 pd = bucket[i3];
            int2 pe = bucket[i4]; int2 pf = bucket[i5];
            int2 pg = bucket[i6]; int2 ph = bucket[i7];
            if (i0 >= len) pa = make_int2(0, 0);   // w=0 -> fma is identity
            if (i1 >= len) pb = make_int2(0, 0);
            if (i2 >= len) pc = make_int2(0, 0);
            if (i3 >= len) pd = make_int2(0, 0);
            if (i4 >= len) pe = make_int2(0, 0);
            if (i5 >= len) pf = make_int2(0, 0);
            if (i6 >= len) pg = make_int2(0, 0);
            if (i7 >= len) ph = make_int2(0, 0);
            float4 va = *(const float4*)(h + pa.x * 64 + q * 4);
            float4 vb = *(const float4*)(h + pb.x * 64 + q * 4);
            float4 vc = *(const float4*)(h + pc.x * 64 + q * 4);
            float4 vd = *(const float4*)(h + pd.x * 64 + q * 4);
            float4 ve = *(const float4*)(h + pe.x * 64 + q * 4);
            float4 vf = *(const float4*)(h + pf.x * 64 + q * 4);
            float4 vg = *(const float4*)(h + pg.x * 64 + q * 4);
            float4 vh = *(const float4*)(h + ph.x * 64 + q * 4);
            float wa = __int_as_float(pa.y), wb = __int_as_float(pb.y);
            float wc = __int_as_float(pc.y), wd = __int_as_float(pd.y);
            float we = __int_as_float(pe.y), wf = __int_as_float(pf.y);
            float wg = __int_as_float(pg.y), wh = __int_as_float(ph.y);
            acc4.x = fmaf(va.x, wa, acc4.x); acc4.y = fmaf(va.y, wa, acc4.y);
            acc4.z = fmaf(va.z, wa, acc4.z); acc4.w = fmaf(va.w, wa, acc4.w);
            acc4.x = fmaf(vb.x, wb, acc4.x); acc4.y = fmaf(vb.y, wb, acc4.y);
            acc4.z = fmaf(vb.z, wb, acc4.z); acc4.w = fmaf(vb.w, wb, acc4.w);
            acc4.x = fmaf(vc.x, wc, acc4.x); acc4.y = fmaf(vc.y, wc, acc4.y);
            acc4.z = fmaf(vc.z, wc, acc4.z); acc4.w = fmaf(vc.w, wc, acc4.w);
            acc4.x = fmaf(vd.x, wd, acc4.x); acc4.y = fmaf(vd.y, wd, acc4.y);
            acc4.z = fmaf(vd.z, wd, acc4.z); acc4.w = fmaf(vd.w, wd, acc4.w);
            acc4.x = fmaf(ve.x, we, acc4.x); acc4.y = fmaf(ve.y, we, acc4.y);
            acc4.z = fmaf(ve.z, we, acc4.z); acc4.w = fmaf(ve.w, we, acc4.w);
            acc4.x = fmaf(vf.x, wf, acc4.x); acc4.y = fmaf(vf.y, wf, acc4.y);
            acc4.z = fmaf(vf.z, wf, acc4.z); acc4.w = fmaf(vf.w, wf, acc4.w);
            acc4.x = fmaf(vg.x, wg, acc4.x); acc4.y = fmaf(vg.y, wg, acc4.y);
            acc4.z = fmaf(vg.z, wg, acc4.z); acc4.w = fmaf(vg.w, wg, acc4.w);
            acc4.x = fmaf(vh.x, wh, acc4.x); acc4.y = fmaf(vh.y, wh, acc4.y);
            acc4.z = fmaf(vh.z, wh, acc4.z); acc4.w = fmaf(vh.w, wh, acc4.w);
        }
        acc4.x += __shfl_xor(acc4.x, 16); acc4.y += __shfl_xor(acc4.y, 16);
        acc4.z += __shfl_xor(acc4.z, 16); acc4.w += __shfl_xor(acc4.w, 16);
        acc4.x += __shfl_xor(acc4.x, 32); acc4.y += __shfl_xor(acc4.y, 32);
        acc4.z += __shfl_xor(acc4.z, 32); acc4.w += __shfl_xor(acc4.w, 32);
        if (eslot == 0) *(float4*)(&a2[nn][q * 4]) = acc4;
        hrow[nn][c] = h[n * 64 + c];
        __syncthreads();
        // GEMV: 4 groups of 128 threads; group g computes nodes 2g, 2g+1 over full kk.
        int g = t >> 7, c2 = t & 127;
        if (c2 < NCLUST) {
            int na = 2 * g, nb2 = 2 * g + 1;
            float s0 = b2s[c2], s1 = s0;
#pragma unroll 8
            for (int kk = 0; kk < 64; ++kk) {
                float wr = wsrel[kk * 100 + c2];
                float wo = w2t_root[kk * 100 + c2];
                s0 = fmaf(a2[na][kk], wr, fmaf(hrow[na][kk], wo, s0));
                s1 = fmaf(a2[nb2][kk], wr, fmaf(hrow[nb2][kk], wo, s1));
            }
            logits[na][c2] = s0;
            logits[nb2][c2] = s1;
        }
        __syncthreads();
        float v0 = logits[nn][c];
        float v1 = (c < NCLUST - 64) ? logits[nn][64 + c] : -INFINITY;
        float m = fmaxf(v0, v1);
#pragma unroll
        for (int off = 32; off > 0; off >>= 1) m = fmaxf(m, __shfl_xor(m, off));
        float e0 = __expf(v0 - m);
        float e1 = (c < NCLUST - 64) ? __expf(v1 - m) : 0.f;
        float s = e0 + e1;
#pragma unroll
        for (int off = 32; off > 0; off >>= 1) s += __shfl_xor(s, off);
        float inv = 1.f / s;
        out[n * NCLUST + c] = e0 * inv;
        if (c < NCLUST - 64) out[n * NCLUST + 64 + c] = e1 * inv;
    } else {
        // ---- scalars mc, o (512 threads; entries live in t<256)
        float* red = wsrel;
        float sv = 0.f;
        if (t < 256)
            for (int bb = 0; bb < NBLK_N; ++bb) sv += sspart[bb * 256 + t];
        red[t] = sv * sv;
        __syncthreads();
        for (int s = 256; s > 0; s >>= 1) {
            if (t < s) red[t] += red[t + s];
            __syncthreads();
        }
        float ssnorm = sqrtf(red[0]);
        __syncthreads();
        float diff = (t < 256) ? (sv / ssnorm - ((t % 17 == 0) ? 0.25f : 0.f)) : 0.f;
        red[t] = diff * diff;
        __syncthreads();
        for (int s = 256; s > 0; s >>= 1) {
            if (t < s) red[t] += red[t + s];
            __syncthreads();
        }
        if (t == 0) {
            out[N_NODES * NCLUST + 0] = -(scal[0] / scal[1]);
            out[N_NODES * NCLUST + 1] = sqrtf(red[0]);
        }
    }
}

extern "C" void kernel_launch(void* const* d_in, const int* in_sizes, int n_in,
                              void* d_out, int out_size, void* d_ws, size_t ws_size,
                              hipStream_t stream) {
    const float* x       = (const float*)d_in[0];
    const int*   ei      = (const int*)d_in[1];
    const float* ew      = (const float*)d_in[2];
    const float* W1_rel  = (const float*)d_in[3];
    const float* W1_root = (const float*)d_in[4];
    const float* b1      = (const float*)d_in[5];
    const float* W2_rel  = (const float*)d_in[6];
    const float* W2_root = (const float*)d_in[7];
    const float* b2      = (const float*)d_in[8];
    float* out = (float*)d_out;
    int*   wsi = (int*)d_ws;

    int*   bincnt  = wsi + OFF_BINCNT;
    float* scal    = (float*)(wsi + OFF_SCAL);
    int*   count   = wsi + OFF_COUNT;
    float* sspart  = (float*)(wsi + OFF_SSPART);
    float* norm2   = (float*)(wsi + OFF_NORM2);
    float* w2trel  = (float*)(wsi + OFF_W2TREL);
    float* w2troot = (float*)(wsi + OFF_W2TROOT);
    float* smc     = (float*)(wsi + OFF_SMC);
    float* h       = (float*)(wsi + OFF_H);
    int2*  srcw    = (int2*)(wsi + OFF_SRCW);
    int2*  binbuf  = (int2*)(wsi + OFF_BINBUF);

    hipMemsetAsync(wsi, 0, ZERO_ELEMS * sizeof(int), stream);   // bincnt + scal only
    binA_kernel<<<NBLK_E + NBLK_N + 2, 256, 0, stream>>>(x, ei, ew, smc, norm2, bincnt, binbuf,
                                                         W2_rel, W2_root, w2trel, w2troot);
    binB_kernel<<<NBIN + NBLK_N + NBLK_E, 256, 0, stream>>>(binbuf, bincnt, count, srcw,
                                                            smc, sspart, ei, ew, norm2, scal);
    fused1_kernel<<<NBLK_F1, 256, 0, stream>>>(x, srcw, count, W1_rel, W1_root, b1, h);
    fused2_finalize_kernel<<<NBLK_F2 + 1, 512, 0, stream>>>(h, srcw, count, w2trel, w2troot,
                                                            b2, out, sspart, scal);
}